// Round 6
// baseline (2513.759 us; speedup 1.0000x reference)
//
#include <hip/hip_runtime.h>
#include <hip/hip_bf16.h>
#include <math.h>

#define D_MODEL 1024
#define NH      16
#define HD      64
#define DFF     4096
#define SEQ     1024
#define BATCH   4
#define TOK     (BATCH*SEQ)   // 4096 tokens
#define MAXSTEPS 24

typedef __hip_bfloat16 bf16;

__device__ __forceinline__ float b2f(bf16 v){ return __bfloat162float(v); }
__device__ __forceinline__ bf16  f2b(float v){ return __float2bfloat16(v); }

// ---------------------------------------------------------------------------
// Tiled GEMM: C[M,N] = A[M,K] (bf16 ws) * B[K,N] (fp32 input) + bias (fp32)
// 64x64 tile, BK=16, 256 threads, 4x4 microtile, fp32 accumulate.
// EPI: 0 = store fp32, 1 = store bf16, 2 = exact-GELU -> bf16
// ---------------------------------------------------------------------------
template<int EPI>
__global__ __launch_bounds__(256)
void gemm_kernel(const bf16* __restrict__ A, const float* __restrict__ B,
                 const float* __restrict__ bias, void* __restrict__ outv,
                 int M, int N, int K)
{
    __shared__ float As[16][68];   // [k][m]
    __shared__ float Bs[16][68];   // [k][n]
    const int tid = threadIdx.x;
    const int tx = tid & 15, ty = tid >> 4;
    const int row0 = blockIdx.y * 64, col0 = blockIdx.x * 64;

    float acc[4][4] = {};

    for (int k0 = 0; k0 < K; k0 += 16) {
        #pragma unroll
        for (int u = 0; u < 4; ++u) {
            int lin = tid + 256 * u;
            int r = lin >> 4, c = lin & 15;          // A tile 64 rows x 16 k
            As[c][r] = b2f(A[(row0 + r) * K + k0 + c]);
        }
        #pragma unroll
        for (int u = 0; u < 4; ++u) {
            int lin = tid + 256 * u;
            int kr = lin >> 6, nc = lin & 63;        // B tile 16 k x 64 n
            Bs[kr][nc] = B[(k0 + kr) * N + col0 + nc];
        }
        __syncthreads();
        #pragma unroll
        for (int kk = 0; kk < 16; ++kk) {
            float av[4], bv[4];
            *(float4*)av = *(const float4*)&As[kk][ty * 4];
            *(float4*)bv = *(const float4*)&Bs[kk][tx * 4];
            #pragma unroll
            for (int i = 0; i < 4; ++i)
                #pragma unroll
                for (int j = 0; j < 4; ++j)
                    acc[i][j] += av[i] * bv[j];
        }
        __syncthreads();
    }

    #pragma unroll
    for (int i = 0; i < 4; ++i) {
        int r = row0 + ty * 4 + i;
        #pragma unroll
        for (int j = 0; j < 4; ++j) {
            int c = col0 + tx * 4 + j;
            float v = acc[i][j] + bias[c];
            if (EPI == 0) {
                ((float*)outv)[r * N + c] = v;
            } else if (EPI == 1) {
                ((bf16*)outv)[r * N + c] = f2b(v);
            } else { // exact GELU
                float g = 0.5f * v * (1.0f + erff(v * 0.70710678118654752f));
                ((bf16*)outv)[r * N + c] = f2b(g);
            }
        }
    }
}

// ---------------------------------------------------------------------------
// Gate GEMM: g = sigmoid([x|orig] @ Wg + bg); xw = x*(1-g) + orig*g + se[step]
// fp32 inputs; bf16 output.
// ---------------------------------------------------------------------------
__global__ __launch_bounds__(256)
void gate_kernel(const float* __restrict__ x, const float* __restrict__ orig,
                 const float* __restrict__ Wg, const float* __restrict__ bg,
                 const int* __restrict__ step_ptr, const float* __restrict__ se,
                 bf16* __restrict__ out)
{
    __shared__ float As[16][68];
    __shared__ float Bs[16][68];
    const int tid = threadIdx.x;
    const int tx = tid & 15, ty = tid >> 4;
    const int row0 = blockIdx.y * 64, col0 = blockIdx.x * 64;
    const int K = 2 * D_MODEL, N = D_MODEL;

    float acc[4][4] = {};

    for (int k0 = 0; k0 < K; k0 += 16) {
        #pragma unroll
        for (int u = 0; u < 4; ++u) {
            int lin = tid + 256 * u;
            int r = lin >> 4, c = lin & 15;
            int gr = row0 + r, gc = k0 + c;
            As[c][r] = (gc < D_MODEL) ? x[gr * D_MODEL + gc]
                                      : orig[gr * D_MODEL + gc - D_MODEL];
        }
        #pragma unroll
        for (int u = 0; u < 4; ++u) {
            int lin = tid + 256 * u;
            int kr = lin >> 6, nc = lin & 63;
            Bs[kr][nc] = Wg[(k0 + kr) * N + col0 + nc];
        }
        __syncthreads();
        #pragma unroll
        for (int kk = 0; kk < 16; ++kk) {
            float av[4], bv[4];
            *(float4*)av = *(const float4*)&As[kk][ty * 4];
            *(float4*)bv = *(const float4*)&Bs[kk][tx * 4];
            #pragma unroll
            for (int i = 0; i < 4; ++i)
                #pragma unroll
                for (int j = 0; j < 4; ++j)
                    acc[i][j] += av[i] * bv[j];
        }
        __syncthreads();
    }

    int st = step_ptr[0];
    st = st < 0 ? 0 : (st > MAXSTEPS - 1 ? MAXSTEPS - 1 : st);

    #pragma unroll
    for (int i = 0; i < 4; ++i) {
        int r = row0 + ty * 4 + i;
        #pragma unroll
        for (int j = 0; j < 4; ++j) {
            int c = col0 + tx * 4 + j;
            float z = acc[i][j] + bg[c];
            float g = 1.0f / (1.0f + expf(-z));
            float xf = x[r * D_MODEL + c];
            float of = orig[r * D_MODEL + c];
            out[r * D_MODEL + c] = f2b(xf * (1.0f - g) + of * g + se[st * D_MODEL + c]);
        }
    }
}

// ---------------------------------------------------------------------------
// Attention: one block handles 8 consecutive q rows for one (b,h).
// qkv layout: (T, 3072) bf16 with [q|k|v] each (H, HD) per token.
// out: (T, D) bf16, column h*64+d  (i.e. (B,S,H,hd) flattened).
// ---------------------------------------------------------------------------
__global__ __launch_bounds__(256)
void attn_kernel(const bf16* __restrict__ qkv, const float* __restrict__ relb,
                 bf16* __restrict__ out)
{
    __shared__ float qs[8][64];
    __shared__ float sc[8][SEQ];        // 32 KB
    __shared__ float part[4][8][64];    // 8 KB
    __shared__ float red[256];
    __shared__ float rowinv[8];

    const int tid = threadIdx.x;
    const int blk = blockIdx.x;         // B * H * (S/8)
    const int qb  = blk & 127;
    const int h   = (blk >> 7) & 15;
    const int b   = blk >> 11;
    const int t0  = b * SEQ + qb * 8;

    for (int idx = tid; idx < 512; idx += 256) {
        int r = idx >> 6, d = idx & 63;
        qs[r][d] = b2f(qkv[(t0 + r) * 3072 + h * 64 + d]);
    }
    __syncthreads();

    // scores + rel-pos bias
    for (int kj = tid; kj < SEQ; kj += 256) {
        const bf16* kp = qkv + (b * SEQ + kj) * 3072 + D_MODEL + h * 64;
        float s[8] = {};
        for (int d = 0; d < 64; ++d) {
            float kd = b2f(kp[d]);
            #pragma unroll
            for (int r = 0; r < 8; ++r) s[r] += qs[r][d] * kd;
        }
        #pragma unroll
        for (int r = 0; r < 8; ++r) {
            int qi = qb * 8 + r;
            int rel = qi - kj + (SEQ - 1);       // in [0, 2046], no clip needed
            sc[r][kj] = s[r] * 0.125f + relb[rel];
        }
    }
    __syncthreads();

    // softmax per row
    for (int r = 0; r < 8; ++r) {
        float lm = -1e30f;
        for (int kj = tid; kj < SEQ; kj += 256) lm = fmaxf(lm, sc[r][kj]);
        red[tid] = lm; __syncthreads();
        for (int s2 = 128; s2 > 0; s2 >>= 1) {
            if (tid < s2) red[tid] = fmaxf(red[tid], red[tid + s2]);
            __syncthreads();
        }
        float m = red[0];
        __syncthreads();
        float ls = 0.f;
        for (int kj = tid; kj < SEQ; kj += 256) {
            float p = expf(sc[r][kj] - m);
            sc[r][kj] = p; ls += p;
        }
        red[tid] = ls; __syncthreads();
        for (int s2 = 128; s2 > 0; s2 >>= 1) {
            if (tid < s2) red[tid] += red[tid + s2];
            __syncthreads();
        }
        if (tid == 0) rowinv[r] = 1.0f / red[0];
        __syncthreads();
    }

    // P @ V (chunked over k)
    const int d  = tid & 63;
    const int ch = tid >> 6;
    float acc[8] = {};
    const bf16* vp = qkv + (b * SEQ + ch * 256) * 3072 + 2 * D_MODEL + h * 64 + d;
    for (int kk = 0; kk < 256; ++kk) {
        float vv = b2f(vp[kk * 3072]);
        int kj = ch * 256 + kk;
        #pragma unroll
        for (int r = 0; r < 8; ++r) acc[r] += sc[r][kj] * vv;
    }
    #pragma unroll
    for (int r = 0; r < 8; ++r) part[ch][r][d] = acc[r];
    __syncthreads();
    if (tid < 64) {
        #pragma unroll
        for (int r = 0; r < 8; ++r) {
            float o = (part[0][r][tid] + part[1][r][tid] +
                       part[2][r][tid] + part[3][r][tid]) * rowinv[r];
            out[(t0 + r) * D_MODEL + h * 64 + tid] = f2b(o);
        }
    }
}

// ---------------------------------------------------------------------------
// Fused residual + LayerNorm over rows of 1024: out = LN(a + add)*g + b
// a bf16 (ws); add fp32; g,b fp32 inputs. OUT_BF16 selects output dtype.
// In-place safe over `add`/`out` (per-thread read-before-write + barrier).
// ---------------------------------------------------------------------------
template<bool OUT_BF16>
__global__ __launch_bounds__(256)
void ln_kernel(const bf16* __restrict__ a, const float* __restrict__ add,
               const float* __restrict__ g, const float* __restrict__ bb,
               void* __restrict__ outv)
{
    __shared__ float red[256];
    __shared__ float red2[256];
    const int row = blockIdx.x;
    const int tid = threadIdx.x;
    float s[4];
    float lsum = 0.f, lsq = 0.f;
    #pragma unroll
    for (int u = 0; u < 4; ++u) {
        int i = tid + 256 * u;
        float v = b2f(a[row * D_MODEL + i]) + add[row * D_MODEL + i];
        s[u] = v; lsum += v; lsq += v * v;
    }
    red[tid] = lsum; red2[tid] = lsq; __syncthreads();
    for (int s2 = 128; s2 > 0; s2 >>= 1) {
        if (tid < s2) { red[tid] += red[tid + s2]; red2[tid] += red2[tid + s2]; }
        __syncthreads();
    }
    float mean = red[0] * (1.0f / D_MODEL);
    float var  = red2[0] * (1.0f / D_MODEL) - mean * mean;
    float rs = rsqrtf(var + 1e-5f);
    #pragma unroll
    for (int u = 0; u < 4; ++u) {
        int i = tid + 256 * u;
        float o = (s[u] - mean) * rs * g[i] + bb[i];
        if (OUT_BF16) ((bf16*)outv)[row * D_MODEL + i] = f2b(o);
        else          ((float*)outv)[row * D_MODEL + i] = o;
    }
}

// ---------------------------------------------------------------------------
extern "C" void kernel_launch(void* const* d_in, const int* in_sizes, int n_in,
                              void* d_out, int out_size, void* d_ws, size_t ws_size,
                              hipStream_t stream)
{
    const float* x     = (const float*)d_in[0];
    const float* orig  = (const float*)d_in[1];
    const int*   step  = (const int*)  d_in[2];
    const float* se    = (const float*)d_in[3];
    const float* Wqkv  = (const float*)d_in[4];
    const float* bqkv  = (const float*)d_in[5];
    const float* Wout  = (const float*)d_in[6];
    const float* bout  = (const float*)d_in[7];
    const float* Wg    = (const float*)d_in[8];
    const float* bg    = (const float*)d_in[9];
    const float* relb  = (const float*)d_in[10];
    const float* W1    = (const float*)d_in[11];
    const float* b1    = (const float*)d_in[12];
    const float* W2    = (const float*)d_in[13];
    const float* b2    = (const float*)d_in[14];
    const float* ln1g  = (const float*)d_in[15];
    const float* ln1b  = (const float*)d_in[16];
    const float* ln2g  = (const float*)d_in[17];
    const float* ln2b  = (const float*)d_in[18];

    // Workspace layout — 40 MB total (bf16 intermediates):
    //   [0,  8): xw   bf16 (T,1024)  gate+step output; LN1 output (in place)
    //   [8, 32): qkv  bf16 (T,3072)
    //   [32,40): attn bf16 (T,1024)
    //   [8, 40): h    bf16 (T,4096)  FFN hidden (qkv+attn dead by then)
    // tmp (projection outputs) = d_out itself as FP32 (T,1024) = 16 MB.
    // Output is FP32 (reference returns float32; harness reads d_out as fp32).
    char* ws = (char*)d_ws;
    bf16*  xw   = (bf16*)(ws);
    bf16*  qkvb = (bf16*)(ws + (8u  << 20));
    bf16*  attn = (bf16*)(ws + (32u << 20));
    bf16*  h    = (bf16*)(ws + (8u  << 20));
    float* tmp  = (float*)d_out;

    dim3 blk(256);

    // 1. gated residual injection + step embedding -> xw (bf16)
    gate_kernel<<<dim3(D_MODEL / 64, TOK / 64), blk, 0, stream>>>(
        x, orig, Wg, bg, step, se, xw);

    // 2. QKV projection -> qkvb (bf16, T x 3072)
    gemm_kernel<1><<<dim3(3 * D_MODEL / 64, TOK / 64), blk, 0, stream>>>(
        xw, Wqkv, bqkv, qkvb, TOK, 3 * D_MODEL, D_MODEL);

    // 3. attention -> attn (bf16, T x D in (B,S,H,hd) order)
    attn_kernel<<<BATCH * NH * (SEQ / 8), blk, 0, stream>>>(qkvb, relb, attn);

    // 4. output projection -> tmp (= d_out, fp32)
    gemm_kernel<0><<<dim3(D_MODEL / 64, TOK / 64), blk, 0, stream>>>(
        attn, Wout, bout, tmp, TOK, D_MODEL, D_MODEL);

    // 5. LN1(xw + tmp) -> xw (bf16, in place over xw)
    ln_kernel<true><<<TOK, blk, 0, stream>>>(xw, tmp, ln1g, ln1b, xw);

    // 6. FFN up + exact GELU -> h (bf16, T x DFF; clobbers qkv+attn, both dead)
    gemm_kernel<2><<<dim3(DFF / 64, TOK / 64), blk, 0, stream>>>(
        xw, W1, b1, h, TOK, DFF, D_MODEL);

    // 7. FFN down -> tmp (= d_out, fp32)
    gemm_kernel<0><<<dim3(D_MODEL / 64, TOK / 64), blk, 0, stream>>>(
        h, W2, b2, tmp, TOK, D_MODEL, DFF);

    // 8. LN2(xw + tmp) -> d_out (FP32, in place over tmp)
    ln_kernel<false><<<TOK, blk, 0, stream>>>(xw, tmp, ln2g, ln2b, d_out);
}

// Round 7
// 1093.625 us; speedup vs baseline: 2.2986x; 2.2986x over previous
//
#include <hip/hip_runtime.h>
#include <hip/hip_bf16.h>
#include <math.h>

#define D_MODEL 1024
#define NH      16
#define HD      64
#define DFF     4096
#define SEQ     1024
#define BATCH   4
#define TOK     (BATCH*SEQ)   // 4096 tokens
#define MAXSTEPS 24

typedef __hip_bfloat16 bf16;
typedef __attribute__((ext_vector_type(8))) short short8;   // 8 bf16 = one MFMA frag
typedef __attribute__((ext_vector_type(4))) float floatx4;  // MFMA acc

__device__ __forceinline__ float b2f(bf16 v){ return __bfloat162float(v); }
__device__ __forceinline__ bf16  f2b(float v){ return __float2bfloat16(v); }

__device__ __forceinline__ void gload_lds16(const bf16* g, bf16* l){
    __builtin_amdgcn_global_load_lds((const __attribute__((address_space(1))) void*)g,
                                     (__attribute__((address_space(3))) void*)l, 16, 0, 0);
}

// ---------------------------------------------------------------------------
// MFMA GEMM: C[M,N] = A[M,K] (bf16, K-contig) * Bt[N,K]^T (bf16, K-contig) + bias
// 128x128 tile, BK=32, 256 thr = 4 waves (2x2 of 64x64), 16x16x32 bf16 MFMA.
// LDS: 16B chunks, chunk(m,q) at slot m*4 + (q ^ ((m>>1)&3))  -> staging stays
// coalesced (within-64B permutation) and ds_read_b128 is 2-way/free on banks.
// EPI: 0 = fp32 store, 1 = bf16 store, 2 = exact-GELU -> bf16
// ---------------------------------------------------------------------------
template<int EPI>
__global__ __launch_bounds__(256)
void mfma_gemm(const bf16* __restrict__ A, const bf16* __restrict__ Bt,
               const float* __restrict__ bias, void* __restrict__ outv,
               int M, int N, int K)
{
    __shared__ bf16 As[128 * 32];
    __shared__ bf16 Bs[128 * 32];
    const int tid  = threadIdx.x;
    const int lane = tid & 63;
    const int w    = tid >> 6;
    const int wm   = w & 1, wn = w >> 1;
    const int fr   = lane & 15;     // row/col within 16-tile
    const int q    = lane >> 4;     // k-quad (8 bf16 each)
    const int row0 = blockIdx.y * 128, col0 = blockIdx.x * 128;

    floatx4 acc[4][4] = {};

    for (int k0 = 0; k0 < K; k0 += 32) {
        __syncthreads();
        #pragma unroll
        for (int p = 0; p < 2; ++p) {
            int s  = p * 256 + tid;            // chunk slot [0,512)
            int m  = s >> 2;
            int qg = (s & 3) ^ ((m >> 1) & 3); // swizzle inverse
            const bf16* gA = A  + (size_t)(row0 + m) * K + k0 + qg * 8;
            const bf16* gB = Bt + (size_t)(col0 + m) * K + k0 + qg * 8;
            bf16* lbase = (bf16*)((s - lane) * 8);  // chunk*8 elems, wave-uniform
            gload_lds16(gA, As + (size_t)((s - lane) * 8) - 0);
            gload_lds16(gB, Bs + (size_t)((s - lane) * 8) - 0);
            (void)lbase;
        }
        __syncthreads();

        short8 af[4], bfg[4];
        #pragma unroll
        for (int t = 0; t < 4; ++t) {
            int ml = wm * 64 + t * 16 + fr;
            af[t]  = *(const short8*)(As + (size_t)(ml * 4 + (q ^ ((ml >> 1) & 3))) * 8);
            int nl = wn * 64 + t * 16 + fr;
            bfg[t] = *(const short8*)(Bs + (size_t)(nl * 4 + (q ^ ((nl >> 1) & 3))) * 8);
        }
        #pragma unroll
        for (int i = 0; i < 4; ++i)
            #pragma unroll
            for (int j = 0; j < 4; ++j)
                acc[i][j] = __builtin_amdgcn_mfma_f32_16x16x32_bf16(af[i], bfg[j], acc[i][j], 0, 0, 0);
    }

    // epilogue: C/D frag col=lane&15, row=(lane>>4)*4+reg
    float bv[4];
    #pragma unroll
    for (int nt = 0; nt < 4; ++nt) bv[nt] = bias[col0 + wn * 64 + nt * 16 + fr];
    #pragma unroll
    for (int mt = 0; mt < 4; ++mt) {
        #pragma unroll
        for (int nt = 0; nt < 4; ++nt) {
            int col = col0 + wn * 64 + nt * 16 + fr;
            #pragma unroll
            for (int r = 0; r < 4; ++r) {
                int row = row0 + wm * 64 + mt * 16 + q * 4 + r;
                float v = acc[mt][nt][r] + bv[nt];
                if (EPI == 0) {
                    ((float*)outv)[(size_t)row * N + col] = v;
                } else if (EPI == 1) {
                    ((bf16*)outv)[(size_t)row * N + col] = f2b(v);
                } else {
                    float g = 0.5f * v * (1.0f + erff(v * 0.70710678118654752f));
                    ((bf16*)outv)[(size_t)row * N + col] = f2b(g);
                }
            }
        }
    }
}

// ---------------------------------------------------------------------------
// Transpose-convert: W (K x N, fp32, row-major) -> WT (N x K, bf16, row-major)
// ---------------------------------------------------------------------------
__global__ __launch_bounds__(256)
void transpose_kernel(const float* __restrict__ W, bf16* __restrict__ WT,
                      int K, int N)
{
    __shared__ float t[32][33];
    const int tx = threadIdx.x & 31, ty = threadIdx.x >> 5;  // 32 x 8
    const int n0 = blockIdx.x * 32, k0 = blockIdx.y * 32;
    #pragma unroll
    for (int i = 0; i < 4; ++i)
        t[ty + i * 8][tx] = W[(size_t)(k0 + ty + i * 8) * N + n0 + tx];
    __syncthreads();
    #pragma unroll
    for (int i = 0; i < 4; ++i)
        WT[(size_t)(n0 + ty + i * 8) * K + k0 + tx] = f2b(t[tx][ty + i * 8]);
}

// ---------------------------------------------------------------------------
// Build concat A for the gate GEMM: xcat[t, 0:1024]=x[t], [1024:2048]=orig[t]
// ---------------------------------------------------------------------------
__global__ __launch_bounds__(256)
void xcat_kernel(const float* __restrict__ x, const float* __restrict__ orig,
                 bf16* __restrict__ xcat)
{
    int i = blockIdx.x * 256 + threadIdx.x;       // group of 4 elems; T*256 groups
    float4 xv = ((const float4*)x)[i];
    float4 ov = ((const float4*)orig)[i];
    int t = i >> 8, c4 = (i & 255) * 4;
    bf16* px = xcat + (size_t)t * 2048 + c4;
    px[0] = f2b(xv.x); px[1] = f2b(xv.y); px[2] = f2b(xv.z); px[3] = f2b(xv.w);
    bf16* po = px + 1024;
    po[0] = f2b(ov.x); po[1] = f2b(ov.y); po[2] = f2b(ov.z); po[3] = f2b(ov.w);
}

// ---------------------------------------------------------------------------
// Gate mix: xw = x*(1-sig(z)) + orig*sig(z) + se[step]   (z = xcat@Wg + bg)
// ---------------------------------------------------------------------------
__global__ __launch_bounds__(256)
void gatemix_kernel(const float* __restrict__ x, const float* __restrict__ orig,
                    const float* __restrict__ z, const int* __restrict__ step_ptr,
                    const float* __restrict__ se, bf16* __restrict__ xw)
{
    int i = blockIdx.x * 256 + threadIdx.x;   // T*1024 elements
    int st = step_ptr[0];
    st = st < 0 ? 0 : (st > MAXSTEPS - 1 ? MAXSTEPS - 1 : st);
    float g = 1.0f / (1.0f + expf(-z[i]));
    float v = x[i] * (1.0f - g) + orig[i] * g + se[st * D_MODEL + (i & 1023)];
    xw[i] = f2b(v);
}

// ---------------------------------------------------------------------------
// Attention (unchanged from R6): one block = 8 q rows for one (b,h).
// ---------------------------------------------------------------------------
__global__ __launch_bounds__(256)
void attn_kernel(const bf16* __restrict__ qkv, const float* __restrict__ relb,
                 bf16* __restrict__ out)
{
    __shared__ float qs[8][64];
    __shared__ float sc[8][SEQ];
    __shared__ float part[4][8][64];
    __shared__ float red[256];
    __shared__ float rowinv[8];

    const int tid = threadIdx.x;
    const int blk = blockIdx.x;
    const int qb  = blk & 127;
    const int h   = (blk >> 7) & 15;
    const int b   = blk >> 11;
    const int t0  = b * SEQ + qb * 8;

    for (int idx = tid; idx < 512; idx += 256) {
        int r = idx >> 6, d = idx & 63;
        qs[r][d] = b2f(qkv[(t0 + r) * 3072 + h * 64 + d]);
    }
    __syncthreads();

    for (int kj = tid; kj < SEQ; kj += 256) {
        const bf16* kp = qkv + (b * SEQ + kj) * 3072 + D_MODEL + h * 64;
        float s[8] = {};
        for (int d = 0; d < 64; ++d) {
            float kd = b2f(kp[d]);
            #pragma unroll
            for (int r = 0; r < 8; ++r) s[r] += qs[r][d] * kd;
        }
        #pragma unroll
        for (int r = 0; r < 8; ++r) {
            int qi = qb * 8 + r;
            sc[r][kj] = s[r] * 0.125f + relb[qi - kj + (SEQ - 1)];
        }
    }
    __syncthreads();

    for (int r = 0; r < 8; ++r) {
        float lm = -1e30f;
        for (int kj = tid; kj < SEQ; kj += 256) lm = fmaxf(lm, sc[r][kj]);
        red[tid] = lm; __syncthreads();
        for (int s2 = 128; s2 > 0; s2 >>= 1) {
            if (tid < s2) red[tid] = fmaxf(red[tid], red[tid + s2]);
            __syncthreads();
        }
        float m = red[0];
        __syncthreads();
        float ls = 0.f;
        for (int kj = tid; kj < SEQ; kj += 256) {
            float p = expf(sc[r][kj] - m);
            sc[r][kj] = p; ls += p;
        }
        red[tid] = ls; __syncthreads();
        for (int s2 = 128; s2 > 0; s2 >>= 1) {
            if (tid < s2) red[tid] += red[tid + s2];
            __syncthreads();
        }
        if (tid == 0) rowinv[r] = 1.0f / red[0];
        __syncthreads();
    }

    const int d  = tid & 63;
    const int ch = tid >> 6;
    float acc[8] = {};
    const bf16* vp = qkv + (b * SEQ + ch * 256) * 3072 + 2 * D_MODEL + h * 64 + d;
    for (int kk = 0; kk < 256; ++kk) {
        float vv = b2f(vp[kk * 3072]);
        int kj = ch * 256 + kk;
        #pragma unroll
        for (int r = 0; r < 8; ++r) acc[r] += sc[r][kj] * vv;
    }
    #pragma unroll
    for (int r = 0; r < 8; ++r) part[ch][r][d] = acc[r];
    __syncthreads();
    if (tid < 64) {
        #pragma unroll
        for (int r = 0; r < 8; ++r) {
            float o = (part[0][r][tid] + part[1][r][tid] +
                       part[2][r][tid] + part[3][r][tid]) * rowinv[r];
            out[(t0 + r) * D_MODEL + h * 64 + tid] = f2b(o);
        }
    }
}

// ---------------------------------------------------------------------------
// Fused residual + LayerNorm: out = LN(a + add)*g + b   (a bf16, add fp32)
// ---------------------------------------------------------------------------
template<bool OUT_BF16>
__global__ __launch_bounds__(256)
void ln_kernel(const bf16* __restrict__ a, const float* __restrict__ add,
               const float* __restrict__ g, const float* __restrict__ bb,
               void* __restrict__ outv)
{
    __shared__ float red[256];
    __shared__ float red2[256];
    const int row = blockIdx.x;
    const int tid = threadIdx.x;
    float s[4];
    float lsum = 0.f, lsq = 0.f;
    #pragma unroll
    for (int u = 0; u < 4; ++u) {
        int i = tid + 256 * u;
        float v = b2f(a[row * D_MODEL + i]) + add[row * D_MODEL + i];
        s[u] = v; lsum += v; lsq += v * v;
    }
    red[tid] = lsum; red2[tid] = lsq; __syncthreads();
    for (int s2 = 128; s2 > 0; s2 >>= 1) {
        if (tid < s2) { red[tid] += red[tid + s2]; red2[tid] += red2[tid + s2]; }
        __syncthreads();
    }
    float mean = red[0] * (1.0f / D_MODEL);
    float var  = red2[0] * (1.0f / D_MODEL) - mean * mean;
    float rs = rsqrtf(var + 1e-5f);
    #pragma unroll
    for (int u = 0; u < 4; ++u) {
        int i = tid + 256 * u;
        float o = (s[u] - mean) * rs * g[i] + bb[i];
        if (OUT_BF16) ((bf16*)outv)[row * D_MODEL + i] = f2b(o);
        else          ((float*)outv)[row * D_MODEL + i] = o;
    }
}

// ---------------------------------------------------------------------------
extern "C" void kernel_launch(void* const* d_in, const int* in_sizes, int n_in,
                              void* d_out, int out_size, void* d_ws, size_t ws_size,
                              hipStream_t stream)
{
    const float* x     = (const float*)d_in[0];
    const float* orig  = (const float*)d_in[1];
    const int*   step  = (const int*)  d_in[2];
    const float* se    = (const float*)d_in[3];
    const float* Wqkv  = (const float*)d_in[4];
    const float* bqkv  = (const float*)d_in[5];
    const float* Wout  = (const float*)d_in[6];
    const float* bout  = (const float*)d_in[7];
    const float* Wg    = (const float*)d_in[8];
    const float* bg    = (const float*)d_in[9];
    const float* relb  = (const float*)d_in[10];
    const float* W1    = (const float*)d_in[11];
    const float* b1    = (const float*)d_in[12];
    const float* W2    = (const float*)d_in[13];
    const float* b2    = (const float*)d_in[14];
    const float* ln1g  = (const float*)d_in[15];
    const float* ln1b  = (const float*)d_in[16];
    const float* ln2g  = (const float*)d_in[17];
    const float* ln2b  = (const float*)d_in[18];

    // Workspace (76 MB; R2 demonstrated >=80 MB is safe):
    //  [ 0, 4): WgT   bf16 (1024 x 2048)
    //  [ 4,10): WqkvT bf16 (3072 x 1024)
    //  [10,12): WoutT bf16 (1024 x 1024)
    //  [12,20): W1T   bf16 (4096 x 1024)
    //  [20,28): W2T   bf16 (1024 x 4096)
    //  [28,44): xcat  bf16 (T x 2048)   -- dead after gate GEMM
    //  [28,36): xw    bf16 (T x 1024)   -- written after xcat dead
    //  [36,44): attnb bf16 (T x 1024)
    //  [44,68): qkvb  bf16 (T x 3072)   -- dead after attention
    //  [44,76): h     bf16 (T x 4096)
    //  tmp fp32 (T x 1024, 16 MB) = d_out itself.
    char* ws = (char*)d_ws;
    bf16* WgT   = (bf16*)(ws);
    bf16* WqkvT = (bf16*)(ws + ( 4u << 20));
    bf16* WoutT = (bf16*)(ws + (10u << 20));
    bf16* W1T   = (bf16*)(ws + (12u << 20));
    bf16* W2T   = (bf16*)(ws + (20u << 20));
    bf16* xcat  = (bf16*)(ws + (28u << 20));
    bf16* xw    = (bf16*)(ws + (28u << 20));
    bf16* attnb = (bf16*)(ws + (36u << 20));
    bf16* qkvb  = (bf16*)(ws + (44u << 20));
    bf16* h     = (bf16*)(ws + (44u << 20));
    float* tmp  = (float*)d_out;

    dim3 blk(256);

    // 0. weight transpose-converts (fp32 KxN -> bf16 NxK) + xcat build
    transpose_kernel<<<dim3(1024/32, 2048/32), blk, 0, stream>>>(Wg,   WgT,   2048, 1024);
    transpose_kernel<<<dim3(3072/32, 1024/32), blk, 0, stream>>>(Wqkv, WqkvT, 1024, 3072);
    transpose_kernel<<<dim3(1024/32, 1024/32), blk, 0, stream>>>(Wout, WoutT, 1024, 1024);
    transpose_kernel<<<dim3(4096/32, 1024/32), blk, 0, stream>>>(W1,   W1T,   1024, 4096);
    transpose_kernel<<<dim3(1024/32, 4096/32), blk, 0, stream>>>(W2,   W2T,   4096, 1024);
    xcat_kernel<<<TOK, blk, 0, stream>>>(x, orig, xcat);

    // 1. gate pre-activation z -> tmp (fp32)
    mfma_gemm<0><<<dim3(D_MODEL/128, TOK/128), blk, 0, stream>>>(
        xcat, WgT, bg, tmp, TOK, D_MODEL, 2*D_MODEL);

    // 2. gated mix + step embedding -> xw (bf16)
    gatemix_kernel<<<TOK*D_MODEL/256, blk, 0, stream>>>(x, orig, tmp, step, se, xw);

    // 3. QKV projection -> qkvb
    mfma_gemm<1><<<dim3(3*D_MODEL/128, TOK/128), blk, 0, stream>>>(
        xw, WqkvT, bqkv, qkvb, TOK, 3*D_MODEL, D_MODEL);

    // 4. attention -> attnb
    attn_kernel<<<BATCH*NH*(SEQ/8), blk, 0, stream>>>(qkvb, relb, attnb);

    // 5. output projection -> tmp (fp32)
    mfma_gemm<0><<<dim3(D_MODEL/128, TOK/128), blk, 0, stream>>>(
        attnb, WoutT, bout, tmp, TOK, D_MODEL, D_MODEL);

    // 6. LN1(xw + tmp) -> xw (bf16, in place)
    ln_kernel<true><<<TOK, blk, 0, stream>>>(xw, tmp, ln1g, ln1b, xw);

    // 7. FFN up + exact GELU -> h (qkvb/attnb dead)
    mfma_gemm<2><<<dim3(DFF/128, TOK/128), blk, 0, stream>>>(
        xw, W1T, b1, h, TOK, DFF, D_MODEL);

    // 8. FFN down -> tmp (fp32)
    mfma_gemm<0><<<dim3(D_MODEL/128, TOK/128), blk, 0, stream>>>(
        h, W2T, b2, tmp, TOK, D_MODEL, DFF);

    // 9. LN2(xw + tmp) -> d_out (fp32, in place over tmp)
    ln_kernel<false><<<TOK, blk, 0, stream>>>(xw, tmp, ln2g, ln2b, d_out);
}

// Round 8
// 528.671 us; speedup vs baseline: 4.7549x; 2.0686x over previous
//
#include <hip/hip_runtime.h>
#include <hip/hip_bf16.h>
#include <math.h>

#define D_MODEL 1024
#define NH      16
#define HD      64
#define DFF     4096
#define SEQ     1024
#define BATCH   4
#define TOK     (BATCH*SEQ)   // 4096 tokens
#define MAXSTEPS 24

typedef __hip_bfloat16 bf16;
typedef __attribute__((ext_vector_type(8))) short short8;   // 8 bf16 = one MFMA frag
typedef __attribute__((ext_vector_type(4))) float floatx4;  // MFMA acc

__device__ __forceinline__ float b2f(bf16 v){ return __bfloat162float(v); }
__device__ __forceinline__ bf16  f2b(float v){ return __float2bfloat16(v); }

__device__ __forceinline__ void gload_lds16(const bf16* g, bf16* l){
    __builtin_amdgcn_global_load_lds((const __attribute__((address_space(1))) void*)g,
                                     (__attribute__((address_space(3))) void*)l, 16, 0, 0);
}

// ---------------------------------------------------------------------------
// MFMA GEMM (unchanged from R7): C = A[M,K](bf16) * Bt[N,K]^T (bf16) + bias
// ---------------------------------------------------------------------------
template<int EPI>
__global__ __launch_bounds__(256)
void mfma_gemm(const bf16* __restrict__ A, const bf16* __restrict__ Bt,
               const float* __restrict__ bias, void* __restrict__ outv,
               int M, int N, int K)
{
    __shared__ bf16 As[128 * 32];
    __shared__ bf16 Bs[128 * 32];
    const int tid  = threadIdx.x;
    const int lane = tid & 63;
    const int w    = tid >> 6;
    const int wm   = w & 1, wn = w >> 1;
    const int fr   = lane & 15;
    const int q    = lane >> 4;
    const int row0 = blockIdx.y * 128, col0 = blockIdx.x * 128;

    floatx4 acc[4][4] = {};

    for (int k0 = 0; k0 < K; k0 += 32) {
        __syncthreads();
        #pragma unroll
        for (int p = 0; p < 2; ++p) {
            int s  = p * 256 + tid;
            int m  = s >> 2;
            int qg = (s & 3) ^ ((m >> 1) & 3);
            const bf16* gA = A  + (size_t)(row0 + m) * K + k0 + qg * 8;
            const bf16* gB = Bt + (size_t)(col0 + m) * K + k0 + qg * 8;
            gload_lds16(gA, As + (size_t)s * 8);
            gload_lds16(gB, Bs + (size_t)s * 8);
        }
        __syncthreads();

        short8 af[4], bfg[4];
        #pragma unroll
        for (int t = 0; t < 4; ++t) {
            int ml = wm * 64 + t * 16 + fr;
            af[t]  = *(const short8*)(As + (size_t)(ml * 4 + (q ^ ((ml >> 1) & 3))) * 8);
            int nl = wn * 64 + t * 16 + fr;
            bfg[t] = *(const short8*)(Bs + (size_t)(nl * 4 + (q ^ ((nl >> 1) & 3))) * 8);
        }
        #pragma unroll
        for (int i = 0; i < 4; ++i)
            #pragma unroll
            for (int j = 0; j < 4; ++j)
                acc[i][j] = __builtin_amdgcn_mfma_f32_16x16x32_bf16(af[i], bfg[j], acc[i][j], 0, 0, 0);
    }

    float bv[4];
    #pragma unroll
    for (int nt = 0; nt < 4; ++nt) bv[nt] = bias[col0 + wn * 64 + nt * 16 + fr];
    #pragma unroll
    for (int mt = 0; mt < 4; ++mt) {
        #pragma unroll
        for (int nt = 0; nt < 4; ++nt) {
            int col = col0 + wn * 64 + nt * 16 + fr;
            #pragma unroll
            for (int r = 0; r < 4; ++r) {
                int row = row0 + wm * 64 + mt * 16 + q * 4 + r;
                float v = acc[mt][nt][r] + bv[nt];
                if (EPI == 0) {
                    ((float*)outv)[(size_t)row * N + col] = v;
                } else if (EPI == 1) {
                    ((bf16*)outv)[(size_t)row * N + col] = f2b(v);
                } else {
                    float g = 0.5f * v * (1.0f + erff(v * 0.70710678118654752f));
                    ((bf16*)outv)[(size_t)row * N + col] = f2b(g);
                }
            }
        }
    }
}

// ---------------------------------------------------------------------------
// Weight transpose-convert: W (K x N fp32) -> WT (N x K bf16)
// ---------------------------------------------------------------------------
__global__ __launch_bounds__(256)
void transpose_kernel(const float* __restrict__ W, bf16* __restrict__ WT,
                      int K, int N)
{
    __shared__ float t[32][33];
    const int tx = threadIdx.x & 31, ty = threadIdx.x >> 5;
    const int n0 = blockIdx.x * 32, k0 = blockIdx.y * 32;
    #pragma unroll
    for (int i = 0; i < 4; ++i)
        t[ty + i * 8][tx] = W[(size_t)(k0 + ty + i * 8) * N + n0 + tx];
    __syncthreads();
    #pragma unroll
    for (int i = 0; i < 4; ++i)
        WT[(size_t)(n0 + ty + i * 8) * K + k0 + tx] = f2b(t[tx][ty + i * 8]);
}

// ---------------------------------------------------------------------------
// V transpose: qkv (T,3072) v-part -> Vt (B,H,64,S) bf16
// ---------------------------------------------------------------------------
__global__ __launch_bounds__(256)
void vtrans_kernel(const bf16* __restrict__ qkv, bf16* __restrict__ Vt)
{
    __shared__ float t[32][33];
    const int blk = blockIdx.x;
    const int dt = blk & 1;
    const int st = (blk >> 1) & 31;
    const int h  = (blk >> 6) & 15;
    const int b  = blk >> 10;
    const int tx = threadIdx.x & 31, ty = threadIdx.x >> 5;
    #pragma unroll
    for (int i = 0; i < 4; ++i)
        t[ty + i * 8][tx] = b2f(qkv[(size_t)(b * SEQ + st * 32 + ty + i * 8) * 3072
                                    + 2048 + h * 64 + dt * 32 + tx]);
    __syncthreads();
    #pragma unroll
    for (int i = 0; i < 4; ++i)
        Vt[(size_t)((b * NH + h) * 64 + dt * 32 + ty + i * 8) * SEQ + st * 32 + tx]
            = f2b(t[tx][ty + i * 8]);
}

// ---------------------------------------------------------------------------
// xcat / gatemix (unchanged from R7)
// ---------------------------------------------------------------------------
__global__ __launch_bounds__(256)
void xcat_kernel(const float* __restrict__ x, const float* __restrict__ orig,
                 bf16* __restrict__ xcat)
{
    int i = blockIdx.x * 256 + threadIdx.x;
    float4 xv = ((const float4*)x)[i];
    float4 ov = ((const float4*)orig)[i];
    int t = i >> 8, c4 = (i & 255) * 4;
    bf16* px = xcat + (size_t)t * 2048 + c4;
    px[0] = f2b(xv.x); px[1] = f2b(xv.y); px[2] = f2b(xv.z); px[3] = f2b(xv.w);
    bf16* po = px + 1024;
    po[0] = f2b(ov.x); po[1] = f2b(ov.y); po[2] = f2b(ov.z); po[3] = f2b(ov.w);
}

__global__ __launch_bounds__(256)
void gatemix_kernel(const float* __restrict__ x, const float* __restrict__ orig,
                    const float* __restrict__ z, const int* __restrict__ step_ptr,
                    const float* __restrict__ se, bf16* __restrict__ xw)
{
    int i = blockIdx.x * 256 + threadIdx.x;
    int st = step_ptr[0];
    st = st < 0 ? 0 : (st > MAXSTEPS - 1 ? MAXSTEPS - 1 : st);
    float g = 1.0f / (1.0f + expf(-z[i]));
    float v = x[i] * (1.0f - g) + orig[i] * g + se[st * D_MODEL + (i & 1023)];
    xw[i] = f2b(v);
}

// ---------------------------------------------------------------------------
// MFMA flash attention. Block = 64 q-rows of one (b,h); 4 waves x 16 rows.
// K-tiles of 128 keys, online softmax. qkv (T,3072); Vt (B,H,64,S).
// out (T,1024) bf16 at column h*64+d.
// LDS: Ks [128 key][64 dim] chunk-swizzled; aliased by per-wave P [16][128]
// after the S-phase (extra barrier). Vs [64 dim][128 key] chunk-swizzled.
// ---------------------------------------------------------------------------
__global__ __launch_bounds__(256)
void fattn_kernel(const bf16* __restrict__ qkv, const bf16* __restrict__ Vt,
                  const float* __restrict__ relb, bf16* __restrict__ out)
{
    __shared__ bf16 KPs[128 * 64];   // K tile; later aliased as P (4 waves x 16x128)
    __shared__ bf16 Vs [64 * 128];   // V^T tile

    const int tid  = threadIdx.x;
    const int lane = tid & 63;
    const int w    = tid >> 6;
    const int fr   = lane & 15;
    const int quad = lane >> 4;

    const int qt = blockIdx.x & 15;
    const int h  = (blockIdx.x >> 4) & 15;
    const int b  = blockIdx.x >> 8;
    const int bq = b * SEQ;
    const int bh = b * NH + h;

    // Q A-frags for this wave's 16 rows (row m = fr), k = dim
    const int qrow = bq + qt * 64 + w * 16 + fr;
    short8 qf[2];
    {
        const bf16* qp = qkv + (size_t)qrow * 3072 + h * 64 + quad * 8;
        qf[0] = *(const short8*)(qp);
        qf[1] = *(const short8*)(qp + 32);
    }

    float m_run[4], l_run[4];
    floatx4 accO[4];
    #pragma unroll
    for (int r = 0; r < 4; ++r) { m_run[r] = -1e30f; l_run[r] = 0.f; }
    #pragma unroll
    for (int nt = 0; nt < 4; ++nt) accO[nt] = (floatx4){0.f, 0.f, 0.f, 0.f};

    for (int k0 = 0; k0 < SEQ; k0 += 128) {
        __syncthreads();   // prev iter's P/V reads done before restaging
        // stage K tile: 128 keys x 8 chunks (16B), source-permuted so LDS is linear
        #pragma unroll
        for (int it = 0; it < 4; ++it) {
            int s = it * 256 + tid;
            int key = s >> 3, cs = s & 7;
            int c = cs ^ (key & 7);
            const bf16* src = qkv + (size_t)(bq + k0 + key) * 3072 + 1024 + h * 64 + c * 8;
            gload_lds16(src, KPs + (size_t)s * 8);
        }
        // stage V^T tile: 64 dims x 16 chunks
        #pragma unroll
        for (int it = 0; it < 4; ++it) {
            int s = it * 256 + tid;
            int row = s >> 4, cs = s & 15;
            int c = cs ^ (row & 15);
            const bf16* src = Vt + (size_t)(bh * 64 + row) * SEQ + k0 + c * 8;
            gload_lds16(src, Vs + (size_t)s * 8);
        }
        __syncthreads();

        // S = Q K^T : 8 key-tiles of 16, K-dim 64 (2 MFMA steps)
        floatx4 accS[8];
        #pragma unroll
        for (int t = 0; t < 8; ++t) accS[t] = (floatx4){0.f, 0.f, 0.f, 0.f};
        #pragma unroll
        for (int t = 0; t < 8; ++t) {
            int row = t * 16 + fr;
            #pragma unroll
            for (int ks = 0; ks < 2; ++ks) {
                int slot = (ks * 4 + quad) ^ (row & 7);
                short8 kf = *(const short8*)(KPs + (size_t)row * 64 + slot * 8);
                accS[t] = __builtin_amdgcn_mfma_f32_16x16x32_bf16(qf[ks], kf, accS[t], 0, 0, 0);
            }
        }

        // scale + rel-pos bias, local row max
        float sv[8][4], mloc[4];
        #pragma unroll
        for (int r = 0; r < 4; ++r) mloc[r] = -1e30f;
        #pragma unroll
        for (int t = 0; t < 8; ++t) {
            int kj = k0 + t * 16 + fr;
            #pragma unroll
            for (int r = 0; r < 4; ++r) {
                int qi = qt * 64 + w * 16 + quad * 4 + r;
                float v = accS[t][r] * 0.125f + relb[qi - kj + (SEQ - 1)];
                sv[t][r] = v;
                mloc[r] = fmaxf(mloc[r], v);
            }
        }
        #pragma unroll
        for (int r = 0; r < 4; ++r) {
            float v = mloc[r];
            v = fmaxf(v, __shfl_xor(v, 1));
            v = fmaxf(v, __shfl_xor(v, 2));
            v = fmaxf(v, __shfl_xor(v, 4));
            v = fmaxf(v, __shfl_xor(v, 8));
            mloc[r] = v;
        }
        float alpha[4], lloc[4];
        #pragma unroll
        for (int r = 0; r < 4; ++r) {
            float mn = fmaxf(m_run[r], mloc[r]);
            alpha[r] = expf(m_run[r] - mn);
            m_run[r] = mn;
            lloc[r] = 0.f;
        }

        __syncthreads();   // all waves done reading Ks before aliasing as P

        // P = exp(S - m) -> bf16 LDS (A-layout-friendly [row][key], swizzled)
        bf16* Ps = KPs + w * 2048;
        #pragma unroll
        for (int t = 0; t < 8; ++t) {
            int keyl = t * 16 + fr;
            int cbase = keyl >> 3, koff = keyl & 7;
            #pragma unroll
            for (int r = 0; r < 4; ++r) {
                float p = expf(sv[t][r] - m_run[r]);
                lloc[r] += p;
                int row = quad * 4 + r;
                int slot = cbase ^ (row & 15);
                Ps[(size_t)row * 128 + slot * 8 + koff] = f2b(p);
            }
        }
        #pragma unroll
        for (int r = 0; r < 4; ++r) {
            float v = lloc[r];
            v += __shfl_xor(v, 1); v += __shfl_xor(v, 2);
            v += __shfl_xor(v, 4); v += __shfl_xor(v, 8);
            l_run[r] = l_run[r] * alpha[r] + v;
        }
        #pragma unroll
        for (int nt = 0; nt < 4; ++nt)
            #pragma unroll
            for (int r = 0; r < 4; ++r) accO[nt][r] *= alpha[r];

        // O += P @ V : key-dim 128 (4 MFMA steps), 4 dim-tiles of 16
        #pragma unroll
        for (int ks = 0; ks < 4; ++ks) {
            int slotp = (ks * 4 + quad) ^ (fr & 15);
            short8 pf = *(const short8*)(Ps + (size_t)fr * 128 + slotp * 8);
            #pragma unroll
            for (int nt = 0; nt < 4; ++nt) {
                int vrow = nt * 16 + fr;
                int slotv = (ks * 4 + quad) ^ (vrow & 15);
                short8 vf = *(const short8*)(Vs + (size_t)vrow * 128 + slotv * 8);
                accO[nt] = __builtin_amdgcn_mfma_f32_16x16x32_bf16(pf, vf, accO[nt], 0, 0, 0);
            }
        }
    }

    #pragma unroll
    for (int nt = 0; nt < 4; ++nt) {
        int col = h * 64 + nt * 16 + fr;
        #pragma unroll
        for (int r = 0; r < 4; ++r) {
            int t = bq + qt * 64 + w * 16 + quad * 4 + r;
            out[(size_t)t * D_MODEL + col] = f2b(accO[nt][r] / l_run[r]);
        }
    }
}

// ---------------------------------------------------------------------------
// Fused residual + LayerNorm (unchanged from R7)
// ---------------------------------------------------------------------------
template<bool OUT_BF16>
__global__ __launch_bounds__(256)
void ln_kernel(const bf16* __restrict__ a, const float* __restrict__ add,
               const float* __restrict__ g, const float* __restrict__ bb,
               void* __restrict__ outv)
{
    __shared__ float red[256];
    __shared__ float red2[256];
    const int row = blockIdx.x;
    const int tid = threadIdx.x;
    float s[4];
    float lsum = 0.f, lsq = 0.f;
    #pragma unroll
    for (int u = 0; u < 4; ++u) {
        int i = tid + 256 * u;
        float v = b2f(a[row * D_MODEL + i]) + add[row * D_MODEL + i];
        s[u] = v; lsum += v; lsq += v * v;
    }
    red[tid] = lsum; red2[tid] = lsq; __syncthreads();
    for (int s2 = 128; s2 > 0; s2 >>= 1) {
        if (tid < s2) { red[tid] += red[tid + s2]; red2[tid] += red2[tid + s2]; }
        __syncthreads();
    }
    float mean = red[0] * (1.0f / D_MODEL);
    float var  = red2[0] * (1.0f / D_MODEL) - mean * mean;
    float rs = rsqrtf(var + 1e-5f);
    #pragma unroll
    for (int u = 0; u < 4; ++u) {
        int i = tid + 256 * u;
        float o = (s[u] - mean) * rs * g[i] + bb[i];
        if (OUT_BF16) ((bf16*)outv)[row * D_MODEL + i] = f2b(o);
        else          ((float*)outv)[row * D_MODEL + i] = o;
    }
}

// ---------------------------------------------------------------------------
extern "C" void kernel_launch(void* const* d_in, const int* in_sizes, int n_in,
                              void* d_out, int out_size, void* d_ws, size_t ws_size,
                              hipStream_t stream)
{
    const float* x     = (const float*)d_in[0];
    const float* orig  = (const float*)d_in[1];
    const int*   step  = (const int*)  d_in[2];
    const float* se    = (const float*)d_in[3];
    const float* Wqkv  = (const float*)d_in[4];
    const float* bqkv  = (const float*)d_in[5];
    const float* Wout  = (const float*)d_in[6];
    const float* bout  = (const float*)d_in[7];
    const float* Wg    = (const float*)d_in[8];
    const float* bg    = (const float*)d_in[9];
    const float* relb  = (const float*)d_in[10];
    const float* W1    = (const float*)d_in[11];
    const float* b1    = (const float*)d_in[12];
    const float* W2    = (const float*)d_in[13];
    const float* b2    = (const float*)d_in[14];
    const float* ln1g  = (const float*)d_in[15];
    const float* ln1b  = (const float*)d_in[16];
    const float* ln2g  = (const float*)d_in[17];
    const float* ln2b  = (const float*)d_in[18];

    // Workspace (76 MB):
    //  [ 0, 4): WgT   bf16 (1024 x 2048)
    //  [ 4,10): WqkvT bf16 (3072 x 1024)
    //  [10,12): WoutT bf16 (1024 x 1024)
    //  [12,20): W1T   bf16 (4096 x 1024)
    //  [20,28): W2T   bf16 (1024 x 4096)
    //  [28,44): xcat  bf16 (T x 2048)   -- dead after gate GEMM
    //  [28,36): xw    bf16 (T x 1024)
    //  [36,44): attnb bf16 (T x 1024)
    //  [44,68): qkvb  bf16 (T x 3072)   -- dead after attention
    //  [68,76): Vt    bf16 (B,H,64,S)   -- dead after attention
    //  [44,76): h     bf16 (T x 4096)   -- written after attention
    //  tmp fp32 (T x 1024, 16 MB) = d_out itself.
    char* ws = (char*)d_ws;
    bf16* WgT   = (bf16*)(ws);
    bf16* WqkvT = (bf16*)(ws + ( 4u << 20));
    bf16* WoutT = (bf16*)(ws + (10u << 20));
    bf16* W1T   = (bf16*)(ws + (12u << 20));
    bf16* W2T   = (bf16*)(ws + (20u << 20));
    bf16* xcat  = (bf16*)(ws + (28u << 20));
    bf16* xw    = (bf16*)(ws + (28u << 20));
    bf16* attnb = (bf16*)(ws + (36u << 20));
    bf16* qkvb  = (bf16*)(ws + (44u << 20));
    bf16* Vt    = (bf16*)(ws + (68u << 20));
    bf16* h     = (bf16*)(ws + (44u << 20));
    float* tmp  = (float*)d_out;

    dim3 blk(256);

    // 0. weight transpose-converts + xcat build
    transpose_kernel<<<dim3(1024/32, 2048/32), blk, 0, stream>>>(Wg,   WgT,   2048, 1024);
    transpose_kernel<<<dim3(3072/32, 1024/32), blk, 0, stream>>>(Wqkv, WqkvT, 1024, 3072);
    transpose_kernel<<<dim3(1024/32, 1024/32), blk, 0, stream>>>(Wout, WoutT, 1024, 1024);
    transpose_kernel<<<dim3(4096/32, 1024/32), blk, 0, stream>>>(W1,   W1T,   1024, 4096);
    transpose_kernel<<<dim3(1024/32, 4096/32), blk, 0, stream>>>(W2,   W2T,   4096, 1024);
    xcat_kernel<<<TOK, blk, 0, stream>>>(x, orig, xcat);

    // 1. gate pre-activation z -> tmp (fp32)
    mfma_gemm<0><<<dim3(D_MODEL/128, TOK/128), blk, 0, stream>>>(
        xcat, WgT, bg, tmp, TOK, D_MODEL, 2*D_MODEL);

    // 2. gated mix + step embedding -> xw (bf16)
    gatemix_kernel<<<TOK*D_MODEL/256, blk, 0, stream>>>(x, orig, tmp, step, se, xw);

    // 3. QKV projection -> qkvb
    mfma_gemm<1><<<dim3(3*D_MODEL/128, TOK/128), blk, 0, stream>>>(
        xw, WqkvT, bqkv, qkvb, TOK, 3*D_MODEL, D_MODEL);

    // 4a. V transpose -> Vt (B,H,64,S)
    vtrans_kernel<<<BATCH*NH*64, blk, 0, stream>>>(qkvb, Vt);

    // 4b. MFMA flash attention -> attnb
    fattn_kernel<<<BATCH*NH*(SEQ/64), blk, 0, stream>>>(qkvb, Vt, relb, attnb);

    // 5. output projection -> tmp (fp32)
    mfma_gemm<0><<<dim3(D_MODEL/128, TOK/128), blk, 0, stream>>>(
        attnb, WoutT, bout, tmp, TOK, D_MODEL, D_MODEL);

    // 6. LN1(xw + tmp) -> xw (bf16, in place)
    ln_kernel<true><<<TOK, blk, 0, stream>>>(xw, tmp, ln1g, ln1b, xw);

    // 7. FFN up + exact GELU -> h (qkvb/Vt/attnb dead or disjoint)
    mfma_gemm<2><<<dim3(DFF/128, TOK/128), blk, 0, stream>>>(
        xw, W1T, b1, h, TOK, DFF, D_MODEL);

    // 8. FFN down -> tmp (fp32)
    mfma_gemm<0><<<dim3(D_MODEL/128, TOK/128), blk, 0, stream>>>(
        h, W2T, b2, tmp, TOK, D_MODEL, DFF);

    // 9. LN2(xw + tmp) -> d_out (fp32, in place over tmp)
    ln_kernel<false><<<TOK, blk, 0, stream>>>(xw, tmp, ln2g, ln2b, d_out);
}

// Round 9
// 514.032 us; speedup vs baseline: 4.8903x; 1.0285x over previous
//
#include <hip/hip_runtime.h>
#include <hip/hip_bf16.h>
#include <math.h>

#define D_MODEL 1024
#define NH      16
#define HD      64
#define DFF     4096
#define SEQ     1024
#define BATCH   4
#define TOK     (BATCH*SEQ)   // 4096 tokens
#define MAXSTEPS 24

typedef __hip_bfloat16 bf16;
typedef __attribute__((ext_vector_type(8))) short short8;   // 8 bf16 = one MFMA frag
typedef __attribute__((ext_vector_type(4))) float floatx4;  // MFMA acc

__device__ __forceinline__ float b2f(bf16 v){ return __bfloat162float(v); }
__device__ __forceinline__ bf16  f2b(float v){ return __float2bfloat16(v); }

__device__ __forceinline__ void gload_lds16(const bf16* g, bf16* l){
    __builtin_amdgcn_global_load_lds((const __attribute__((address_space(1))) void*)g,
                                     (__attribute__((address_space(3))) void*)l, 16, 0, 0);
}

// ---------------------------------------------------------------------------
// MFMA GEMM: C = A[M,K](bf16) * Bt[N,K]^T (bf16) + bias
// Tile 128 x TN (TN=128 or 64), BK=32, 256 thr = 4 waves in 2x2.
// TN=128: wave tile 64x64 (4x4 frags). TN=64: wave tile 64x32 (4x2 frags);
// grid doubles -> 2 blocks/CU for N=1024 shapes (occupancy fix, R8 post-mortem).
// EPI: 0 = fp32 store, 1 = bf16 store, 2 = exact-GELU -> bf16
// ---------------------------------------------------------------------------
template<int TN, int EPI>
__global__ __launch_bounds__(256)
void mfma_gemm(const bf16* __restrict__ A, const bf16* __restrict__ Bt,
               const float* __restrict__ bias, void* __restrict__ outv,
               int M, int N, int K)
{
    constexpr int NT = TN / 32;          // n-frags per wave
    __shared__ bf16 As[128 * 32];
    __shared__ bf16 Bs[TN * 32];
    const int tid  = threadIdx.x;
    const int lane = tid & 63;
    const int w    = tid >> 6;
    const int wm   = w & 1, wn = w >> 1;
    const int fr   = lane & 15;
    const int q    = lane >> 4;
    const int row0 = blockIdx.y * 128, col0 = blockIdx.x * TN;

    floatx4 acc[4][NT] = {};

    for (int k0 = 0; k0 < K; k0 += 32) {
        __syncthreads();
        #pragma unroll
        for (int p = 0; p < 2; ++p) {
            int s  = p * 256 + tid;            // A chunks [0,512)
            int m  = s >> 2;
            int qg = (s & 3) ^ ((m >> 1) & 3);
            gload_lds16(A + (size_t)(row0 + m) * K + k0 + qg * 8, As + (size_t)s * 8);
        }
        #pragma unroll
        for (int p = 0; p < TN / 64; ++p) {
            int s  = p * 256 + tid;            // B chunks [0, TN*4)
            int m  = s >> 2;
            int qg = (s & 3) ^ ((m >> 1) & 3);
            gload_lds16(Bt + (size_t)(col0 + m) * K + k0 + qg * 8, Bs + (size_t)s * 8);
        }
        __syncthreads();

        short8 af[4], bfg[NT];
        #pragma unroll
        for (int t = 0; t < 4; ++t) {
            int ml = wm * 64 + t * 16 + fr;
            af[t]  = *(const short8*)(As + (size_t)(ml * 4 + (q ^ ((ml >> 1) & 3))) * 8);
        }
        #pragma unroll
        for (int t = 0; t < NT; ++t) {
            int nl = wn * (TN / 2) + t * 16 + fr;
            bfg[t] = *(const short8*)(Bs + (size_t)(nl * 4 + (q ^ ((nl >> 1) & 3))) * 8);
        }
        #pragma unroll
        for (int i = 0; i < 4; ++i)
            #pragma unroll
            for (int j = 0; j < NT; ++j)
                acc[i][j] = __builtin_amdgcn_mfma_f32_16x16x32_bf16(af[i], bfg[j], acc[i][j], 0, 0, 0);
    }

    float bv[NT];
    #pragma unroll
    for (int nt = 0; nt < NT; ++nt) bv[nt] = bias[col0 + wn * (TN / 2) + nt * 16 + fr];
    #pragma unroll
    for (int mt = 0; mt < 4; ++mt) {
        #pragma unroll
        for (int nt = 0; nt < NT; ++nt) {
            int col = col0 + wn * (TN / 2) + nt * 16 + fr;
            #pragma unroll
            for (int r = 0; r < 4; ++r) {
                int row = row0 + wm * 64 + mt * 16 + q * 4 + r;
                float v = acc[mt][nt][r] + bv[nt];
                if (EPI == 0) {
                    ((float*)outv)[(size_t)row * N + col] = v;
                } else if (EPI == 1) {
                    ((bf16*)outv)[(size_t)row * N + col] = f2b(v);
                } else {
                    float g = 0.5f * v * (1.0f + erff(v * 0.70710678118654752f));
                    ((bf16*)outv)[(size_t)row * N + col] = f2b(g);
                }
            }
        }
    }
}

// ---------------------------------------------------------------------------
// Weight transpose-convert: W (K x N fp32) -> WT (N x K bf16)
// ---------------------------------------------------------------------------
__global__ __launch_bounds__(256)
void transpose_kernel(const float* __restrict__ W, bf16* __restrict__ WT,
                      int K, int N)
{
    __shared__ float t[32][33];
    const int tx = threadIdx.x & 31, ty = threadIdx.x >> 5;
    const int n0 = blockIdx.x * 32, k0 = blockIdx.y * 32;
    #pragma unroll
    for (int i = 0; i < 4; ++i)
        t[ty + i * 8][tx] = W[(size_t)(k0 + ty + i * 8) * N + n0 + tx];
    __syncthreads();
    #pragma unroll
    for (int i = 0; i < 4; ++i)
        WT[(size_t)(n0 + ty + i * 8) * K + k0 + tx] = f2b(t[tx][ty + i * 8]);
}

// ---------------------------------------------------------------------------
// V transpose: qkv (T,3072) v-part -> Vt (B,H,64,S) bf16
// ---------------------------------------------------------------------------
__global__ __launch_bounds__(256)
void vtrans_kernel(const bf16* __restrict__ qkv, bf16* __restrict__ Vt)
{
    __shared__ float t[32][33];
    const int blk = blockIdx.x;
    const int dt = blk & 1;
    const int st = (blk >> 1) & 31;
    const int h  = (blk >> 6) & 15;
    const int b  = blk >> 10;
    const int tx = threadIdx.x & 31, ty = threadIdx.x >> 5;
    #pragma unroll
    for (int i = 0; i < 4; ++i)
        t[ty + i * 8][tx] = b2f(qkv[(size_t)(b * SEQ + st * 32 + ty + i * 8) * 3072
                                    + 2048 + h * 64 + dt * 32 + tx]);
    __syncthreads();
    #pragma unroll
    for (int i = 0; i < 4; ++i)
        Vt[(size_t)((b * NH + h) * 64 + dt * 32 + ty + i * 8) * SEQ + st * 32 + tx]
            = f2b(t[tx][ty + i * 8]);
}

// ---------------------------------------------------------------------------
// xcat / gatemix
// ---------------------------------------------------------------------------
__global__ __launch_bounds__(256)
void xcat_kernel(const float* __restrict__ x, const float* __restrict__ orig,
                 bf16* __restrict__ xcat)
{
    int i = blockIdx.x * 256 + threadIdx.x;
    float4 xv = ((const float4*)x)[i];
    float4 ov = ((const float4*)orig)[i];
    int t = i >> 8, c4 = (i & 255) * 4;
    bf16* px = xcat + (size_t)t * 2048 + c4;
    px[0] = f2b(xv.x); px[1] = f2b(xv.y); px[2] = f2b(xv.z); px[3] = f2b(xv.w);
    bf16* po = px + 1024;
    po[0] = f2b(ov.x); po[1] = f2b(ov.y); po[2] = f2b(ov.z); po[3] = f2b(ov.w);
}

__global__ __launch_bounds__(256)
void gatemix_kernel(const float* __restrict__ x, const float* __restrict__ orig,
                    const float* __restrict__ z, const int* __restrict__ step_ptr,
                    const float* __restrict__ se, bf16* __restrict__ xw)
{
    int i = blockIdx.x * 256 + threadIdx.x;
    int st = step_ptr[0];
    st = st < 0 ? 0 : (st > MAXSTEPS - 1 ? MAXSTEPS - 1 : st);
    float g = 1.0f / (1.0f + expf(-z[i]));
    float v = x[i] * (1.0f - g) + orig[i] * g + se[st * D_MODEL + (i & 1023)];
    xw[i] = f2b(v);
}

// ---------------------------------------------------------------------------
// MFMA flash attention (unchanged from R8).
// ---------------------------------------------------------------------------
__global__ __launch_bounds__(256)
void fattn_kernel(const bf16* __restrict__ qkv, const bf16* __restrict__ Vt,
                  const float* __restrict__ relb, bf16* __restrict__ out)
{
    __shared__ bf16 KPs[128 * 64];
    __shared__ bf16 Vs [64 * 128];

    const int tid  = threadIdx.x;
    const int lane = tid & 63;
    const int w    = tid >> 6;
    const int fr   = lane & 15;
    const int quad = lane >> 4;

    const int qt = blockIdx.x & 15;
    const int h  = (blockIdx.x >> 4) & 15;
    const int b  = blockIdx.x >> 8;
    const int bq = b * SEQ;
    const int bh = b * NH + h;

    const int qrow = bq + qt * 64 + w * 16 + fr;
    short8 qf[2];
    {
        const bf16* qp = qkv + (size_t)qrow * 3072 + h * 64 + quad * 8;
        qf[0] = *(const short8*)(qp);
        qf[1] = *(const short8*)(qp + 32);
    }

    float m_run[4], l_run[4];
    floatx4 accO[4];
    #pragma unroll
    for (int r = 0; r < 4; ++r) { m_run[r] = -1e30f; l_run[r] = 0.f; }
    #pragma unroll
    for (int nt = 0; nt < 4; ++nt) accO[nt] = (floatx4){0.f, 0.f, 0.f, 0.f};

    for (int k0 = 0; k0 < SEQ; k0 += 128) {
        __syncthreads();
        #pragma unroll
        for (int it = 0; it < 4; ++it) {
            int s = it * 256 + tid;
            int key = s >> 3, cs = s & 7;
            int c = cs ^ (key & 7);
            const bf16* src = qkv + (size_t)(bq + k0 + key) * 3072 + 1024 + h * 64 + c * 8;
            gload_lds16(src, KPs + (size_t)s * 8);
        }
        #pragma unroll
        for (int it = 0; it < 4; ++it) {
            int s = it * 256 + tid;
            int row = s >> 4, cs = s & 15;
            int c = cs ^ (row & 15);
            const bf16* src = Vt + (size_t)(bh * 64 + row) * SEQ + k0 + c * 8;
            gload_lds16(src, Vs + (size_t)s * 8);
        }
        __syncthreads();

        floatx4 accS[8];
        #pragma unroll
        for (int t = 0; t < 8; ++t) accS[t] = (floatx4){0.f, 0.f, 0.f, 0.f};
        #pragma unroll
        for (int t = 0; t < 8; ++t) {
            int row = t * 16 + fr;
            #pragma unroll
            for (int ks = 0; ks < 2; ++ks) {
                int slot = (ks * 4 + quad) ^ (row & 7);
                short8 kf = *(const short8*)(KPs + (size_t)row * 64 + slot * 8);
                accS[t] = __builtin_amdgcn_mfma_f32_16x16x32_bf16(qf[ks], kf, accS[t], 0, 0, 0);
            }
        }

        float sv[8][4], mloc[4];
        #pragma unroll
        for (int r = 0; r < 4; ++r) mloc[r] = -1e30f;
        #pragma unroll
        for (int t = 0; t < 8; ++t) {
            int kj = k0 + t * 16 + fr;
            #pragma unroll
            for (int r = 0; r < 4; ++r) {
                int qi = qt * 64 + w * 16 + quad * 4 + r;
                float v = accS[t][r] * 0.125f + relb[qi - kj + (SEQ - 1)];
                sv[t][r] = v;
                mloc[r] = fmaxf(mloc[r], v);
            }
        }
        #pragma unroll
        for (int r = 0; r < 4; ++r) {
            float v = mloc[r];
            v = fmaxf(v, __shfl_xor(v, 1));
            v = fmaxf(v, __shfl_xor(v, 2));
            v = fmaxf(v, __shfl_xor(v, 4));
            v = fmaxf(v, __shfl_xor(v, 8));
            mloc[r] = v;
        }
        float alpha[4], lloc[4];
        #pragma unroll
        for (int r = 0; r < 4; ++r) {
            float mn = fmaxf(m_run[r], mloc[r]);
            alpha[r] = expf(m_run[r] - mn);
            m_run[r] = mn;
            lloc[r] = 0.f;
        }

        __syncthreads();

        bf16* Ps = KPs + w * 2048;
        #pragma unroll
        for (int t = 0; t < 8; ++t) {
            int keyl = t * 16 + fr;
            int cbase = keyl >> 3, koff = keyl & 7;
            #pragma unroll
            for (int r = 0; r < 4; ++r) {
                float p = expf(sv[t][r] - m_run[r]);
                lloc[r] += p;
                int row = quad * 4 + r;
                int slot = cbase ^ (row & 15);
                Ps[(size_t)row * 128 + slot * 8 + koff] = f2b(p);
            }
        }
        #pragma unroll
        for (int r = 0; r < 4; ++r) {
            float v = lloc[r];
            v += __shfl_xor(v, 1); v += __shfl_xor(v, 2);
            v += __shfl_xor(v, 4); v += __shfl_xor(v, 8);
            l_run[r] = l_run[r] * alpha[r] + v;
        }
        #pragma unroll
        for (int nt = 0; nt < 4; ++nt)
            #pragma unroll
            for (int r = 0; r < 4; ++r) accO[nt][r] *= alpha[r];

        #pragma unroll
        for (int ks = 0; ks < 4; ++ks) {
            int slotp = (ks * 4 + quad) ^ (fr & 15);
            short8 pf = *(const short8*)(Ps + (size_t)fr * 128 + slotp * 8);
            #pragma unroll
            for (int nt = 0; nt < 4; ++nt) {
                int vrow = nt * 16 + fr;
                int slotv = (ks * 4 + quad) ^ (vrow & 15);
                short8 vf = *(const short8*)(Vs + (size_t)vrow * 128 + slotv * 8);
                accO[nt] = __builtin_amdgcn_mfma_f32_16x16x32_bf16(pf, vf, accO[nt], 0, 0, 0);
            }
        }
    }

    #pragma unroll
    for (int nt = 0; nt < 4; ++nt) {
        int col = h * 64 + nt * 16 + fr;
        #pragma unroll
        for (int r = 0; r < 4; ++r) {
            int t = bq + qt * 64 + w * 16 + quad * 4 + r;
            out[(size_t)t * D_MODEL + col] = f2b(accO[nt][r] / l_run[r]);
        }
    }
}

// ---------------------------------------------------------------------------
// Fused residual + LayerNorm
// ---------------------------------------------------------------------------
template<bool OUT_BF16>
__global__ __launch_bounds__(256)
void ln_kernel(const bf16* __restrict__ a, const float* __restrict__ add,
               const float* __restrict__ g, const float* __restrict__ bb,
               void* __restrict__ outv)
{
    __shared__ float red[256];
    __shared__ float red2[256];
    const int row = blockIdx.x;
    const int tid = threadIdx.x;
    float s[4];
    float lsum = 0.f, lsq = 0.f;
    #pragma unroll
    for (int u = 0; u < 4; ++u) {
        int i = tid + 256 * u;
        float v = b2f(a[row * D_MODEL + i]) + add[row * D_MODEL + i];
        s[u] = v; lsum += v; lsq += v * v;
    }
    red[tid] = lsum; red2[tid] = lsq; __syncthreads();
    for (int s2 = 128; s2 > 0; s2 >>= 1) {
        if (tid < s2) { red[tid] += red[tid + s2]; red2[tid] += red2[tid + s2]; }
        __syncthreads();
    }
    float mean = red[0] * (1.0f / D_MODEL);
    float var  = red2[0] * (1.0f / D_MODEL) - mean * mean;
    float rs = rsqrtf(var + 1e-5f);
    #pragma unroll
    for (int u = 0; u < 4; ++u) {
        int i = tid + 256 * u;
        float o = (s[u] - mean) * rs * g[i] + bb[i];
        if (OUT_BF16) ((bf16*)outv)[row * D_MODEL + i] = f2b(o);
        else          ((float*)outv)[row * D_MODEL + i] = o;
    }
}

// ---------------------------------------------------------------------------
extern "C" void kernel_launch(void* const* d_in, const int* in_sizes, int n_in,
                              void* d_out, int out_size, void* d_ws, size_t ws_size,
                              hipStream_t stream)
{
    const float* x     = (const float*)d_in[0];
    const float* orig  = (const float*)d_in[1];
    const int*   step  = (const int*)  d_in[2];
    const float* se    = (const float*)d_in[3];
    const float* Wqkv  = (const float*)d_in[4];
    const float* bqkv  = (const float*)d_in[5];
    const float* Wout  = (const float*)d_in[6];
    const float* bout  = (const float*)d_in[7];
    const float* Wg    = (const float*)d_in[8];
    const float* bg    = (const float*)d_in[9];
    const float* relb  = (const float*)d_in[10];
    const float* W1    = (const float*)d_in[11];
    const float* b1    = (const float*)d_in[12];
    const float* W2    = (const float*)d_in[13];
    const float* b2    = (const float*)d_in[14];
    const float* ln1g  = (const float*)d_in[15];
    const float* ln1b  = (const float*)d_in[16];
    const float* ln2g  = (const float*)d_in[17];
    const float* ln2b  = (const float*)d_in[18];

    // Workspace (76 MB) — see R7 comments.
    char* ws = (char*)d_ws;
    bf16* WgT   = (bf16*)(ws);
    bf16* WqkvT = (bf16*)(ws + ( 4u << 20));
    bf16* WoutT = (bf16*)(ws + (10u << 20));
    bf16* W1T   = (bf16*)(ws + (12u << 20));
    bf16* W2T   = (bf16*)(ws + (20u << 20));
    bf16* xcat  = (bf16*)(ws + (28u << 20));
    bf16* xw    = (bf16*)(ws + (28u << 20));
    bf16* attnb = (bf16*)(ws + (36u << 20));
    bf16* qkvb  = (bf16*)(ws + (44u << 20));
    bf16* Vt    = (bf16*)(ws + (68u << 20));
    bf16* h     = (bf16*)(ws + (44u << 20));
    float* tmp  = (float*)d_out;

    dim3 blk(256);

    // 0. weight transpose-converts + xcat build
    transpose_kernel<<<dim3(1024/32, 2048/32), blk, 0, stream>>>(Wg,   WgT,   2048, 1024);
    transpose_kernel<<<dim3(3072/32, 1024/32), blk, 0, stream>>>(Wqkv, WqkvT, 1024, 3072);
    transpose_kernel<<<dim3(1024/32, 1024/32), blk, 0, stream>>>(Wout, WoutT, 1024, 1024);
    transpose_kernel<<<dim3(4096/32, 1024/32), blk, 0, stream>>>(W1,   W1T,   1024, 4096);
    transpose_kernel<<<dim3(1024/32, 4096/32), blk, 0, stream>>>(W2,   W2T,   4096, 1024);
    xcat_kernel<<<TOK, blk, 0, stream>>>(x, orig, xcat);

    // 1. gate pre-activation z -> tmp (fp32)   [N=1024 -> TN=64, 512 blocks]
    mfma_gemm<64, 0><<<dim3(D_MODEL/64, TOK/128), blk, 0, stream>>>(
        xcat, WgT, bg, tmp, TOK, D_MODEL, 2*D_MODEL);

    // 2. gated mix + step embedding -> xw (bf16)
    gatemix_kernel<<<TOK*D_MODEL/256, blk, 0, stream>>>(x, orig, tmp, step, se, xw);

    // 3. QKV projection -> qkvb   [N=3072 -> TN=128, 768 blocks]
    mfma_gemm<128, 1><<<dim3(3*D_MODEL/128, TOK/128), blk, 0, stream>>>(
        xw, WqkvT, bqkv, qkvb, TOK, 3*D_MODEL, D_MODEL);

    // 4a. V transpose -> Vt (B,H,64,S)
    vtrans_kernel<<<BATCH*NH*64, blk, 0, stream>>>(qkvb, Vt);

    // 4b. MFMA flash attention -> attnb
    fattn_kernel<<<BATCH*NH*(SEQ/64), blk, 0, stream>>>(qkvb, Vt, relb, attnb);

    // 5. output projection -> tmp (fp32)   [TN=64, 512 blocks]
    mfma_gemm<64, 0><<<dim3(D_MODEL/64, TOK/128), blk, 0, stream>>>(
        attnb, WoutT, bout, tmp, TOK, D_MODEL, D_MODEL);

    // 6. LN1(xw + tmp) -> xw (bf16, in place)
    ln_kernel<true><<<TOK, blk, 0, stream>>>(xw, tmp, ln1g, ln1b, xw);

    // 7. FFN up + exact GELU -> h   [N=4096 -> TN=128, 1024 blocks]
    mfma_gemm<128, 2><<<dim3(DFF/128, TOK/128), blk, 0, stream>>>(
        xw, W1T, b1, h, TOK, DFF, D_MODEL);

    // 8. FFN down -> tmp (fp32)   [N=1024 -> TN=64, 512 blocks]
    mfma_gemm<64, 0><<<dim3(D_MODEL/64, TOK/128), blk, 0, stream>>>(
        h, W2T, b2, tmp, TOK, D_MODEL, DFF);

    // 9. LN2(xw + tmp) -> d_out (fp32, in place over tmp)
    ln_kernel<false><<<TOK, blk, 0, stream>>>(xw, tmp, ln2g, ln2b, d_out);
}